// Round 6
// baseline (317.552 us; speedup 1.0000x reference)
//
#include <hip/hip_runtime.h>
#include <hip/hip_bf16.h>

// KNN_itc: out[b][n] = sum over support descriptors m (441) of top-3 (over 441
// query descriptors) cosine similarities, C=640, bf16 MFMA.
//
// R6:
//  - prep_kernel : block=(img, 64-row hw tile, 128-ch slab), 2800 blocks.
//    One read pass: f32 tile -> LDS + per-thread sumsq partials (atomicAdd to
//    normAll). Packs UNNORMALIZED bf16 in fragment-linear chunks:
//    chunk[(img*28+rb)*20+kt], lane l's MFMA fragment at byte l*16
//    (elem (row=l&15, k=(l>>4)*8+j) at offset l*8+j).
//  - finish_kernel: normAll = rsqrt(sumsq) (0 for pads).
//  - gemm_top3   : 448 threads (7 waves), wave owns 64 rows -> acc 4x4 (64
//    regs, ~120 total -> 4 waves/SIMD, 14 waves/CU). BK=32 slabs: 32 chunks
//    (28 A + 4 B) via global_load_lds w=16; ds_read_b128 all stride-16 linear
//    (conflict-free). Top-3 on v=acc*invq[row]; invs[col] applied post-merge.

#define B_IMGS 75
#define N_CLS  5
#define C_DIM  640
#define HW     441
#define HWP    448
#define NKT    20            // 640 / 32 k-chunks
#define NRB    28            // 448 / 16 row-blocks per image
#define CHUNK  512           // 16 rows x 32 k elems = 1 KiB

typedef __attribute__((ext_vector_type(8))) short  short8;   // 8 x bf16
typedef __attribute__((ext_vector_type(4))) float  float4v;  // MFMA acc

__device__ __forceinline__ void ins3(float& t0, float& t1, float& t2, float v) {
    float m  = fminf(t0, v);
    t0 = fmaxf(t0, v);
    float m2 = fminf(t1, m);
    t1 = fmaxf(t1, m);
    t2 = fmaxf(t2, m2);
}

__device__ __forceinline__ short bf16bits(float x) {
    __hip_bfloat16 h = __float2bfloat16(x);
    return *(short*)&h;
}

__device__ __forceinline__ void glds16(const __hip_bfloat16* g, __hip_bfloat16* l) {
    __builtin_amdgcn_global_load_lds(
        (const __attribute__((address_space(1))) unsigned int*)g,
        (__attribute__((address_space(3))) unsigned int*)l, 16, 0, 0);
}

// ---- prepass: single-read pack + sumsq partials ----
// block = (img 0..79, h0 0..6, cs 0..4); 2800 blocks x 256 threads
__global__ __launch_bounds__(256)
void prep_kernel(const float* __restrict__ q, const float* __restrict__ S,
                 __hip_bfloat16* __restrict__ qn2, __hip_bfloat16* __restrict__ sn2,
                 float* __restrict__ normAll) {
    __shared__ float tile[128][65];     // 33.3 KB -> 4 blocks/CU
    __shared__ float part[4][64];

    int bid = blockIdx.x;
    int img = bid / 35;                 // 0..79 (0..74 = q, 75..79 = S)
    int rem = bid % 35;
    int h0  = rem / 5;                  // 64-row hw tile
    int cs  = rem % 5;                  // 128-channel slab
    const float* src; __hip_bfloat16* dst;
    if (img < B_IMGS) {
        src = q + (size_t)img * C_DIM * HW;
        dst = qn2 + (size_t)img * NRB * NKT * CHUNK;
    } else {
        src = S + (size_t)(img - B_IMGS) * C_DIM * HW;
        dst = sn2 + (size_t)(img - B_IMGS) * NRB * NKT * CHUNK;
    }
    int t  = threadIdx.x;
    int hl = t & 63;
    int p  = t >> 6;                    // 32-channel slice within the slab
    int hw = h0 * 64 + hl;
    bool ok = hw < HW;

    float ss = 0.f;
#pragma unroll
    for (int i = 0; i < 32; ++i) {
        int cl = p * 32 + i;
        float v = ok ? src[(size_t)(cs * 128 + cl) * HW + hw] : 0.f;  // coalesced
        tile[cl][hl] = v;
        ss += v * v;
    }
    part[p][hl] = ss;
    __syncthreads();
    if (t < 64 && (h0 * 64 + t) < HW) {
        float tot = part[0][t] + part[1][t] + part[2][t] + part[3][t];
        atomicAdd(normAll + img * HWP + h0 * 64 + t, tot);
    }

    // pack: fragment-linear chunks, 1KiB coalesced stores
    int rbl   = t >> 6;                 // row-block within the 64-row tile
    int l     = t & 63;
    int seg   = l >> 4;                 // k-segment (8 elems)
    int row16 = l & 15;
#pragma unroll
    for (int ktl = 0; ktl < 4; ++ktl) { // 4 k-chunks in this 128-ch slab
        short8 v;
#pragma unroll
        for (int j = 0; j < 8; ++j)
            v[j] = bf16bits(tile[ktl * 32 + seg * 8 + j][rbl * 16 + row16]);
        size_t coff = ((size_t)(h0 * 4 + rbl) * NKT + cs * 4 + ktl) * CHUNK;
        *(short8*)(dst + coff + l * 8) = v;
    }
}

__global__ void finish_kernel(float* __restrict__ normAll) {
    int i = blockIdx.x * blockDim.x + threadIdx.x;
    if (i < (B_IMGS + N_CLS) * HWP) {
        float s = normAll[i];
        normAll[i] = (s > 0.f) ? rsqrtf(s) : 0.f;
    }
}

// ------------- gemm + fused top-3: 7 waves, BK=32, conflict-free LDS -------------
__global__ __launch_bounds__(448, 4)
void gemm_top3_kernel(const __hip_bfloat16* __restrict__ qn2,
                      const __hip_bfloat16* __restrict__ sn2,
                      const float* __restrict__ normAll,
                      float* __restrict__ out) {
    __shared__ __hip_bfloat16 sbuf[32 * CHUNK];   // 32 KiB: 28 A + 4 B chunks
    __shared__ float mrg[7][64][3];

    // XCD-grouping swizzle: all 35 (n,mt) blocks of image b on one XCD
    int id  = blockIdx.x;
    int xcd = id & 7;
    int j8  = id >> 3;
    int b   = (j8 / 35) * 8 + xcd;
    if (b >= B_IMGS) return;
    int inner = j8 % 35;
    int n  = inner / 7;
    int mt = inner % 7;

    int tid  = threadIdx.x;
    int w    = tid >> 6;                // 0..6
    int l    = tid & 63;
    int c16  = l & 15;
    int quad = l >> 4;

    const __hip_bfloat16* qA = qn2 + (size_t)b * NRB * NKT * CHUNK;
    const __hip_bfloat16* qB = sn2 + ((size_t)n * NRB + mt * 4) * NKT * CHUNK;

    float4v acc[4][4];
#pragma unroll
    for (int r = 0; r < 4; ++r)
#pragma unroll
        for (int j = 0; j < 4; ++j)
            acc[r][j] = (float4v){0.f, 0.f, 0.f, 0.f};

    for (int s = 0; s < NKT; ++s) {
        __syncthreads();                 // prior slab's ds_reads complete
        // stage 32 chunks (28 A + 4 B); c = i*7+w is wave-uniform
#pragma unroll
        for (int i = 0; i < 5; ++i) {
            int c = i * 7 + w;
            if (c < 32) {
                const __hip_bfloat16* g = (c < 28)
                    ? qA + ((size_t)c * NKT + s) * CHUNK
                    : qB + ((size_t)(c - 28) * NKT + s) * CHUNK;
                glds16(g + l * 8, sbuf + c * CHUNK + l * 8);
            }
        }
        __syncthreads();                 // staging visible

        short8 a[4], bf[4];
#pragma unroll
        for (int r = 0; r < 4; ++r)
            a[r] = *(const short8*)(sbuf + (w * 4 + r) * CHUNK + l * 8);   // linear
#pragma unroll
        for (int j = 0; j < 4; ++j)
            bf[j] = *(const short8*)(sbuf + (28 + j) * CHUNK + l * 8);     // linear
#pragma unroll
        for (int r = 0; r < 4; ++r)
#pragma unroll
            for (int j = 0; j < 4; ++j)
                acc[r][j] = __builtin_amdgcn_mfma_f32_16x16x32_bf16(
                    a[r], bf[j], acc[r][j], 0, 0, 0);
    }

    // ---- top-3 over this wave's 64 rows (v = acc * invq[row]) ----
    const float* invq = normAll + (size_t)b * HWP;
    float T0[4], T1[4], T2[4];
#pragma unroll
    for (int j = 0; j < 4; ++j) { T0[j] = -1e30f; T1[j] = -1e30f; T2[j] = -1e30f; }
#pragma unroll
    for (int r = 0; r < 4; ++r)
#pragma unroll
        for (int g = 0; g < 4; ++g) {
            int row = w * 64 + r * 16 + quad * 4 + g;   // C layout: row=quad*4+reg
            float iv = invq[row];                        // L2-hot, row<=447
            bool valid = row < HW;
#pragma unroll
            for (int j = 0; j < 4; ++j) {
                float v = valid ? acc[r][j][g] * iv : -1e30f;
                ins3(T0[j], T1[j], T2[j], v);
            }
        }

    // quad-butterfly merge (rows spread over lane bits 4,5)
#pragma unroll
    for (int j = 0; j < 4; ++j) {
#pragma unroll
        for (int d = 16; d <= 32; d <<= 1) {
            float o0 = __shfl_xor(T0[j], d, 64);
            float o1 = __shfl_xor(T1[j], d, 64);
            float o2 = __shfl_xor(T2[j], d, 64);
            ins3(T0[j], T1[j], T2[j], o0);
            ins3(T0[j], T1[j], T2[j], o1);
            ins3(T0[j], T1[j], T2[j], o2);
        }
    }

    // cross-wave merge via LDS
    if (quad == 0) {
#pragma unroll
        for (int j = 0; j < 4; ++j) {
            mrg[w][j * 16 + c16][0] = T0[j];
            mrg[w][j * 16 + c16][1] = T1[j];
            mrg[w][j * 16 + c16][2] = T2[j];
        }
    }
    __syncthreads();
    if (tid < 64) {
        int col = tid;
        float t0 = mrg[0][col][0], t1 = mrg[0][col][1], t2 = mrg[0][col][2];
#pragma unroll
        for (int ww = 1; ww < 7; ++ww) {
            ins3(t0, t1, t2, mrg[ww][col][0]);
            ins3(t0, t1, t2, mrg[ww][col][1]);
            ins3(t0, t1, t2, mrg[ww][col][2]);
        }
        float isv = normAll[(size_t)(B_IMGS + n) * HWP + mt * 64 + col];  // 0 on pads
        float s = (mt * 64 + col < HW) ? (t0 + t1 + t2) * isv : 0.f;
#pragma unroll
        for (int d = 32; d >= 1; d >>= 1) s += __shfl_xor(s, d, 64);
        if (tid == 0) atomicAdd(&out[b * N_CLS + n], s);
    }
}

extern "C" void kernel_launch(void* const* d_in, const int* in_sizes, int n_in,
                              void* d_out, int out_size, void* d_ws, size_t ws_size,
                              hipStream_t stream) {
    const float* q = (const float*)d_in[0];
    const float* S = (const float*)d_in[1];
    float* out = (float*)d_out;

    char* ws = (char*)d_ws;
    size_t off = 0;
    __hip_bfloat16* qn2 = (__hip_bfloat16*)(ws + off);
    off += (size_t)B_IMGS * NRB * NKT * CHUNK * 2;  off = (off + 255) & ~(size_t)255;
    __hip_bfloat16* sn2 = (__hip_bfloat16*)(ws + off);
    off += (size_t)N_CLS * NRB * NKT * CHUNK * 2;   off = (off + 255) & ~(size_t)255;
    float* normAll = (float*)(ws + off);

    hipMemsetAsync(d_out, 0, (size_t)out_size * sizeof(float), stream);
    hipMemsetAsync(normAll, 0, (size_t)(B_IMGS + N_CLS) * HWP * sizeof(float), stream);

    prep_kernel<<<dim3(80 * 35), dim3(256), 0, stream>>>(q, S, qn2, sn2, normAll);
    finish_kernel<<<dim3(((B_IMGS + N_CLS) * HWP + 255) / 256), dim3(256), 0, stream>>>(normAll);
    // 8 XCD groups x 350 slots; dead blocks (b>=75) exit immediately
    gemm_top3_kernel<<<dim3(8 * 350), dim3(448), 0, stream>>>(qn2, sn2, normAll, out);
}